// Round 1
// baseline (58.665 us; speedup 1.0000x reference)
//
#include <hip/hip_runtime.h>
#include <math.h>

#define EC 32
#define BLOCK 256

// params layout per component e (3 x float4):
//  p0 = (cx, cy, cz, log2|c|)
//  p1 = (Axx, Ayy, Azz, Axy)   A = -0.5*log2(e)*inv_cov, off-diag doubled
//  p2 = (Axz, Ayz, 0, 0)

__global__ void ldif_setup_kernel(const float* __restrict__ constants,
                                  const float* __restrict__ centers,
                                  const float* __restrict__ radii,
                                  const float* __restrict__ rotations,
                                  float4* __restrict__ params) {
    int e = threadIdx.x;
    if (e >= EC) return;
    float r = fabsf(radii[e]);
    float dinv = 1.0f / (r + 1e-8f);
    float rx = rotations[3 * e + 0], ry = rotations[3 * e + 1], rz = rotations[3 * e + 2];
    float cx = cosf(rx), cy = cosf(ry), cz = cosf(rz);
    float sx = sinf(rx), sy = sinf(ry), sz = sinf(rz);
    float R00 = cz * cy, R01 = cz * sy * sx - sz * cx, R02 = cz * sy * cx + sz * sx;
    float R10 = sz * cy, R11 = sz * sy * sx + cz * cx, R12 = sz * sy * cx - cz * sx;
    float R20 = -sy,     R21 = cy * sx,                R22 = cy * cx;
    // inv_cov = R diag(dinv) R^T (d identical across the 3 axes since radii tiled)
    float ic00 = dinv * (R00 * R00 + R01 * R01 + R02 * R02);
    float ic11 = dinv * (R10 * R10 + R11 * R11 + R12 * R12);
    float ic22 = dinv * (R20 * R20 + R21 * R21 + R22 * R22);
    float ic01 = dinv * (R00 * R10 + R01 * R11 + R02 * R12);
    float ic02 = dinv * (R00 * R20 + R01 * R21 + R02 * R22);
    float ic12 = dinv * (R10 * R20 + R11 * R21 + R12 * R22);
    const float NH = -0.72134752044f;  // -0.5 * log2(e)
    float Axx = NH * ic00, Ayy = NH * ic11, Azz = NH * ic22;
    float Axy = 2.0f * NH * ic01, Axz = 2.0f * NH * ic02, Ayz = 2.0f * NH * ic12;
    float lc = log2f(fabsf(constants[e]));
    params[3 * e + 0] = make_float4(centers[3 * e + 0], centers[3 * e + 1], centers[3 * e + 2], lc);
    params[3 * e + 1] = make_float4(Axx, Ayy, Azz, Axy);
    params[3 * e + 2] = make_float4(Axz, Ayz, 0.0f, 0.0f);
}

__global__ __launch_bounds__(BLOCK) void ldif_main_kernel(
    const float* __restrict__ pts,
    const float4* __restrict__ act,     // (EC, N) of float4
    const float* __restrict__ dists,
    const float4* __restrict__ params,
    float4* __restrict__ out,
    float* __restrict__ partials,
    int n) {
    __shared__ float4 sp[EC * 3];
    __shared__ float red[BLOCK];
    int tid = threadIdx.x;
    if (tid < EC * 3) sp[tid] = params[tid];
    __syncthreads();

    long long i = (long long)blockIdx.x * BLOCK + tid;
    float pen = 0.0f;
    if (i < n) {
        float px = pts[3 * i + 0];
        float py = pts[3 * i + 1];
        float pz = pts[3 * i + 2];
        float dl = dists[i] * 1.44269504f;

        float rbf[EC];
        float s = 0.0f;
#pragma unroll
        for (int e = 0; e < EC; ++e) {
            float4 p0 = sp[3 * e + 0];
            float4 p1 = sp[3 * e + 1];
            float4 p2 = sp[3 * e + 2];
            float dx = px - p0.x, dy = py - p0.y, dz = pz - p0.z;
            float q = (p1.x * dx + p1.w * dy + p2.x * dz) * dx
                    + (p1.y * dy + p2.y * dz) * dy
                    + (p1.z * dz) * dz
                    + p0.w;
            float v = __builtin_amdgcn_exp2f(q);  // = |c| * exp(-0.5 diff^T invcov diff)
            rbf[e] = v;
            s += v;
            pen += fabsf(v - 0.005f);
        }
        float rn = __builtin_amdgcn_rcpf(s + 0.01f);

        float a0 = 0.0f, a1 = 0.0f, a2 = 0.0f, a3 = 0.0f;
#pragma unroll 8
        for (int e = 0; e < EC; ++e) {
            float4 a = act[(size_t)e * (size_t)n + (size_t)i];
            float w = rbf[e] * rn;
            float s0 = __builtin_amdgcn_rcpf(1.0f + __builtin_amdgcn_exp2f(-1.44269504f * a.x));
            float s1 = __builtin_amdgcn_rcpf(1.0f + __builtin_amdgcn_exp2f(-1.44269504f * a.y));
            float s2 = __builtin_amdgcn_rcpf(1.0f + __builtin_amdgcn_exp2f(-1.44269504f * a.z));
            float al = 1.0f - __builtin_amdgcn_exp2f(-fmaxf(a.w, 0.0f) * dl);
            a0 += w * s0;
            a1 += w * s1;
            a2 += w * s2;
            a3 += w * al;
        }
        out[i] = make_float4(a0, a1, a2, a3);
    }

    // deterministic block reduction of penalty
    red[tid] = pen;
    __syncthreads();
    for (int st = BLOCK / 2; st > 0; st >>= 1) {
        if (tid < st) red[tid] += red[tid + st];
        __syncthreads();
    }
    if (tid == 0) partials[blockIdx.x] = red[0];
}

__global__ __launch_bounds__(BLOCK) void ldif_reduce_kernel(
    const float* __restrict__ partials, int nparts, float* __restrict__ out, int n) {
    __shared__ double rd[BLOCK];
    int tid = threadIdx.x;
    double s = 0.0;
    for (int j = tid; j < nparts; j += BLOCK) s += (double)partials[j];
    rd[tid] = s;
    __syncthreads();
    for (int st = BLOCK / 2; st > 0; st >>= 1) {
        if (tid < st) rd[tid] += rd[tid + st];
        __syncthreads();
    }
    if (tid == 0) out[0] = (float)(rd[0] / (double)n);
}

extern "C" void kernel_launch(void* const* d_in, const int* in_sizes, int n_in,
                              void* d_out, int out_size, void* d_ws, size_t ws_size,
                              hipStream_t stream) {
    const float* pts       = (const float*)d_in[0];  // (N,3)
    const float* act       = (const float*)d_in[1];  // (EC,N,4)
    const float* dists     = (const float*)d_in[2];  // (N,1)
    const float* constants = (const float*)d_in[3];  // (EC,1)
    const float* centers   = (const float*)d_in[4];  // (EC,3)
    const float* radii     = (const float*)d_in[5];  // (EC,1)
    const float* rotations = (const float*)d_in[6];  // (EC,3)
    float* out = (float*)d_out;

    int n = in_sizes[0] / 3;
    float4* params  = (float4*)d_ws;                       // 384 floats
    float* partials = (float*)((char*)d_ws + 2048);        // nblocks floats

    int nblocks = (n + BLOCK - 1) / BLOCK;

    ldif_setup_kernel<<<1, 64, 0, stream>>>(constants, centers, radii, rotations, params);
    ldif_main_kernel<<<nblocks, BLOCK, 0, stream>>>(
        pts, (const float4*)act, dists, params, (float4*)out, partials, n);
    ldif_reduce_kernel<<<1, BLOCK, 0, stream>>>(partials, nblocks, out + (size_t)4 * n, n);
}

// Round 3
// 51.125 us; speedup vs baseline: 1.1475x; 1.1475x over previous
//
#include <hip/hip_runtime.h>
#include <math.h>

#define EC 32
#define BLOCK 256

typedef float fvec4 __attribute__((ext_vector_type(4)));

__global__ __launch_bounds__(BLOCK) void ldif_main_kernel(
    const float* __restrict__ pts,
    const fvec4* __restrict__ act,      // (EC, N) of float4
    const float* __restrict__ dists,
    const float* __restrict__ constants,
    const float* __restrict__ centers,
    const float* __restrict__ radii,
    const float* __restrict__ rotations,
    fvec4* __restrict__ out,
    float* __restrict__ partials,
    int n) {
    // params layout per component e (3 x float4), computed per-block:
    //  p0 = (cx, cy, cz, log2|c|)
    //  p1 = (Axx, Ayy, Azz, Axy)   A = -0.5*log2(e)*inv_cov, off-diag doubled
    //  p2 = (Axz, Ayz, 0, 0)
    __shared__ float4 sp[EC * 3];
    __shared__ float red[BLOCK];
    int tid = threadIdx.x;
    if (tid < EC) {
        int e = tid;
        float r = fabsf(radii[e]);
        float dinv = 1.0f / (r + 1e-8f);
        float rx = rotations[3 * e + 0], ry = rotations[3 * e + 1], rz = rotations[3 * e + 2];
        float cx = cosf(rx), cy = cosf(ry), cz = cosf(rz);
        float sx = sinf(rx), sy = sinf(ry), sz = sinf(rz);
        float R00 = cz * cy, R01 = cz * sy * sx - sz * cx, R02 = cz * sy * cx + sz * sx;
        float R10 = sz * cy, R11 = sz * sy * sx + cz * cx, R12 = sz * sy * cx - cz * sx;
        float R20 = -sy,     R21 = cy * sx,                R22 = cy * cx;
        float ic00 = dinv * (R00 * R00 + R01 * R01 + R02 * R02);
        float ic11 = dinv * (R10 * R10 + R11 * R11 + R12 * R12);
        float ic22 = dinv * (R20 * R20 + R21 * R21 + R22 * R22);
        float ic01 = dinv * (R00 * R10 + R01 * R11 + R02 * R12);
        float ic02 = dinv * (R00 * R20 + R01 * R21 + R02 * R22);
        float ic12 = dinv * (R10 * R20 + R11 * R21 + R12 * R22);
        const float NH = -0.72134752044f;  // -0.5 * log2(e)
        float lc = log2f(fabsf(constants[e]));
        sp[3 * e + 0] = make_float4(centers[3 * e + 0], centers[3 * e + 1], centers[3 * e + 2], lc);
        sp[3 * e + 1] = make_float4(NH * ic00, NH * ic11, NH * ic22, 2.0f * NH * ic01);
        sp[3 * e + 2] = make_float4(2.0f * NH * ic02, 2.0f * NH * ic12, 0.0f, 0.0f);
    }
    __syncthreads();

    long long i = (long long)blockIdx.x * BLOCK + tid;
    float pen = 0.0f;
    if (i < n) {
        float px = pts[3 * i + 0];
        float py = pts[3 * i + 1];
        float pz = pts[3 * i + 2];
        float dl = dists[i] * 1.44269504f;

        float s = 0.0f;
        float a0 = 0.0f, a1 = 0.0f, a2 = 0.0f, a3 = 0.0f;
#pragma unroll 8
        for (int e = 0; e < EC; ++e) {
            fvec4 a = __builtin_nontemporal_load(&act[(size_t)e * (size_t)n + (size_t)i]);
            float4 p0 = sp[3 * e + 0];
            float4 p1 = sp[3 * e + 1];
            float4 p2 = sp[3 * e + 2];
            float dx = px - p0.x, dy = py - p0.y, dz = pz - p0.z;
            float q = (p1.x * dx + p1.w * dy + p2.x * dz) * dx
                    + (p1.y * dy + p2.y * dz) * dy
                    + (p1.z * dz) * dz
                    + p0.w;
            float v = __builtin_amdgcn_exp2f(q);  // = |c| * exp(-0.5 diff^T invcov diff)
            s += v;
            pen += fabsf(v - 0.005f);
            float s0 = __builtin_amdgcn_rcpf(1.0f + __builtin_amdgcn_exp2f(-1.44269504f * a.x));
            float s1 = __builtin_amdgcn_rcpf(1.0f + __builtin_amdgcn_exp2f(-1.44269504f * a.y));
            float s2 = __builtin_amdgcn_rcpf(1.0f + __builtin_amdgcn_exp2f(-1.44269504f * a.z));
            float al = 1.0f - __builtin_amdgcn_exp2f(-fmaxf(a.w, 0.0f) * dl);
            a0 += v * s0;
            a1 += v * s1;
            a2 += v * s2;
            a3 += v * al;
        }
        float rn = __builtin_amdgcn_rcpf(s + 0.01f);
        fvec4 o;
        o.x = a0 * rn; o.y = a1 * rn; o.z = a2 * rn; o.w = a3 * rn;
        __builtin_nontemporal_store(o, &out[i]);
    }

    // deterministic block reduction of penalty
    red[tid] = pen;
    __syncthreads();
    for (int st = BLOCK / 2; st > 0; st >>= 1) {
        if (tid < st) red[tid] += red[tid + st];
        __syncthreads();
    }
    if (tid == 0) partials[blockIdx.x] = red[0];
}

__global__ __launch_bounds__(BLOCK) void ldif_reduce_kernel(
    const float* __restrict__ partials, int nparts, float* __restrict__ out, int n) {
    __shared__ double rd[BLOCK];
    int tid = threadIdx.x;
    double s = 0.0;
    for (int j = tid; j < nparts; j += BLOCK) s += (double)partials[j];
    rd[tid] = s;
    __syncthreads();
    for (int st = BLOCK / 2; st > 0; st >>= 1) {
        if (tid < st) rd[tid] += rd[tid + st];
        __syncthreads();
    }
    if (tid == 0) out[0] = (float)(rd[0] / (double)n);
}

extern "C" void kernel_launch(void* const* d_in, const int* in_sizes, int n_in,
                              void* d_out, int out_size, void* d_ws, size_t ws_size,
                              hipStream_t stream) {
    const float* pts       = (const float*)d_in[0];  // (N,3)
    const float* act       = (const float*)d_in[1];  // (EC,N,4)
    const float* dists     = (const float*)d_in[2];  // (N,1)
    const float* constants = (const float*)d_in[3];  // (EC,1)
    const float* centers   = (const float*)d_in[4];  // (EC,3)
    const float* radii     = (const float*)d_in[5];  // (EC,1)
    const float* rotations = (const float*)d_in[6];  // (EC,3)
    float* out = (float*)d_out;

    int n = in_sizes[0] / 3;
    float* partials = (float*)d_ws;

    int nblocks = (n + BLOCK - 1) / BLOCK;

    ldif_main_kernel<<<nblocks, BLOCK, 0, stream>>>(
        pts, (const fvec4*)act, dists, constants, centers, radii, rotations,
        (fvec4*)out, partials, n);
    ldif_reduce_kernel<<<1, BLOCK, 0, stream>>>(partials, nblocks, out + (size_t)4 * n, n);
}